// Round 1
// baseline (1685.677 us; speedup 1.0000x reference)
//
#include <hip/hip_runtime.h>
#include <hip/hip_bf16.h>
#include <math.h>

// ---------------------------------------------------------------------------
// Problem: GRU-like cell. B=64, T=512, D=512, H=1024 (fp32).
//   xz = x@kz, xr = x@kr, xh = x@kh   (M=B*T=32768, K=D=512, N=H=1024)
//   scan over t:  r = tanh(xr + h*mr + br) + 1
//                 z = sigmoid(xz + h*mz + bz)
//                 h = z*h + (1-z)*tanh(xh + r*h)     (elementwise in (b,h)!)
// Round 0: fp32 vector-ALU GEMM (no fp32 MFMA on CDNA4) + elementwise scan.
// xh is written directly into d_out; scan reads it and overwrites with h.
// ---------------------------------------------------------------------------

#define BM 128
#define BN 128
#define BK 8
// 256 threads, each computes an 8x8 output tile.

__global__ __launch_bounds__(256) void gemm_f32(
    const float* __restrict__ A,   // [M,K] row-major
    const float* __restrict__ B,   // [K,N] row-major
    float* __restrict__ C,         // [M,N]
    int M, int N, int K)
{
    __shared__ float As[BK][BM];   // stored transposed: As[k][m]
    __shared__ float Bs[BK][BN];

    const int tid = threadIdx.x;
    const int bm = blockIdx.y * BM;
    const int bn = blockIdx.x * BN;

    const int tx = tid & 15;   // 0..15 -> col group (8 cols each)
    const int ty = tid >> 4;   // 0..15 -> row group (8 rows each)

    float acc[8][8];
#pragma unroll
    for (int i = 0; i < 8; i++)
#pragma unroll
        for (int j = 0; j < 8; j++) acc[i][j] = 0.f;

    // A-tile load map: 128 rows x 8 k = 1024 floats = 256 threads x float4
    const int a_row = tid >> 1;          // 0..127
    const int a_k   = (tid & 1) * 4;     // 0 or 4
    // B-tile load map: 8 rows x 128 cols
    const int b_row = tid >> 5;          // 0..7
    const int b_col = (tid & 31) * 4;    // 0..124

    const float* Aptr = A + (size_t)(bm + a_row) * K + a_k;
    const float* Bptr = B + (size_t)b_row * N + bn + b_col;

    for (int k0 = 0; k0 < K; k0 += BK) {
        float4 av = *(const float4*)(Aptr + k0);
        float4 bv = *(const float4*)(Bptr + (size_t)k0 * N);
        As[a_k + 0][a_row] = av.x;
        As[a_k + 1][a_row] = av.y;
        As[a_k + 2][a_row] = av.z;
        As[a_k + 3][a_row] = av.w;
        *(float4*)&Bs[b_row][b_col] = bv;
        __syncthreads();
#pragma unroll
        for (int kk = 0; kk < BK; kk++) {
            float4 a0 = *(const float4*)&As[kk][ty * 8];
            float4 a1 = *(const float4*)&As[kk][ty * 8 + 4];
            float4 b0 = *(const float4*)&Bs[kk][tx * 8];
            float4 b1 = *(const float4*)&Bs[kk][tx * 8 + 4];
            float a[8] = {a0.x, a0.y, a0.z, a0.w, a1.x, a1.y, a1.z, a1.w};
            float b[8] = {b0.x, b0.y, b0.z, b0.w, b1.x, b1.y, b1.z, b1.w};
#pragma unroll
            for (int i = 0; i < 8; i++)
#pragma unroll
                for (int j = 0; j < 8; j++)
                    acc[i][j] = fmaf(a[i], b[j], acc[i][j]);
        }
        __syncthreads();
    }

    float* Cptr = C + (size_t)(bm + ty * 8) * N + bn + tx * 8;
#pragma unroll
    for (int i = 0; i < 8; i++) {
        float4 c0 = {acc[i][0], acc[i][1], acc[i][2], acc[i][3]};
        float4 c1 = {acc[i][4], acc[i][5], acc[i][6], acc[i][7]};
        *(float4*)(Cptr + (size_t)i * N)     = c0;
        *(float4*)(Cptr + (size_t)i * N + 4) = c1;
    }
}

__device__ __forceinline__ float fast_tanh(float x) {
    // tanh(x) = 1 - 2/(exp(2x)+1); __expf -> v_exp_f32. Saturates correctly:
    // x large: exp->inf -> 1; x very negative: exp->0 -> -1.
    return 1.0f - 2.0f / (__expf(2.0f * x) + 1.0f);
}
__device__ __forceinline__ float fast_sigmoid(float x) {
    return 1.0f / (1.0f + __expf(-x));
}

// One thread per (b,h); OUT holds xh on entry, h_t on exit.
__global__ __launch_bounds__(256) void scan_kernel(
    const float* __restrict__ XZ, const float* __restrict__ XR,
    float* __restrict__ OUT,
    const float* __restrict__ mz, const float* __restrict__ mr,
    const float* __restrict__ br, const float* __restrict__ bz,
    int B, int T, int H)
{
    const int gid = blockIdx.x * blockDim.x + threadIdx.x;
    if (gid >= B * H) return;
    const int b = gid / H;
    const int h = gid - b * H;

    const float mzv = mz[h], mrv = mr[h], brv = br[h], bzv = bz[h];
    float hs = 0.f;
    size_t idx = (size_t)b * T * H + h;
    for (int t = 0; t < T; t++, idx += H) {
        const float xz = XZ[idx];
        const float xr = XR[idx];
        const float xh = OUT[idx];
        const float r = fast_tanh(fmaf(hs, mrv, xr) + brv) + 1.0f;
        const float z = fast_sigmoid(fmaf(hs, mzv, xz) + bzv);
        const float hn = fmaf(z, hs, (1.0f - z) * fast_tanh(fmaf(r, hs, xh)));
        OUT[idx] = hn;
        hs = hn;
    }
}

extern "C" void kernel_launch(void* const* d_in, const int* in_sizes, int n_in,
                              void* d_out, int out_size, void* d_ws, size_t ws_size,
                              hipStream_t stream) {
    const float* x  = (const float*)d_in[0];
    const float* kz = (const float*)d_in[1];
    const float* kr = (const float*)d_in[2];
    const float* kh = (const float*)d_in[3];
    const float* mz = (const float*)d_in[4];
    const float* mr = (const float*)d_in[5];
    const float* br = (const float*)d_in[6];
    const float* bz = (const float*)d_in[7];
    float* out = (float*)d_out;

    const int Bb = 64, T = 512, D = 512, H = 1024;
    const int M = Bb * T;  // 32768

    float* XZ = (float*)d_ws;                 // 128 MB
    float* XR = XZ + (size_t)M * H;           // 128 MB

    dim3 grid(H / BN, M / BM);                // 8 x 256 blocks
    gemm_f32<<<grid, 256, 0, stream>>>(x, kz, XZ,  M, H, D);
    gemm_f32<<<grid, 256, 0, stream>>>(x, kr, XR,  M, H, D);
    gemm_f32<<<grid, 256, 0, stream>>>(x, kh, out, M, H, D);

    const int nthr = Bb * H;                  // 65536
    scan_kernel<<<(nthr + 255) / 256, 256, 0, stream>>>(
        XZ, XR, out, mz, mr, br, bz, Bb, T, H);
}

// Round 2
// 645.593 us; speedup vs baseline: 2.6111x; 2.6111x over previous
//
#include <hip/hip_runtime.h>
#include <hip/hip_bf16.h>
#include <math.h>

// ---------------------------------------------------------------------------
// GRU-like cell. B=64, T=512, D=512, H=1024 (fp32).
// Round 1:
//   * fp16 split-precision MFMA GEMM (3-term: Ah*Bh + Ah*Bl + Al*Bh), one
//     fused launch over N=3072 (kz|kr|kh), weights pre-transposed to [N,K].
//     Accuracy ~2^-22 relative -> at/below fp32 accumulation noise.
//   * scan software-pipelined in chunks of 8 timesteps (loads for chunk c+1
//     issued before computing chunk c) to hide HBM latency at 1 wave/SIMD.
// Fallback to round-0 fp32 GEMM if workspace is too small.
// ---------------------------------------------------------------------------

#define M_DIM 32768   // B*T
#define K_DIM 512     // D
#define H_DIM 1024
#define N3    3072    // 3*H

typedef _Float16 half8v __attribute__((ext_vector_type(8)));
typedef _Float16 half4v __attribute__((ext_vector_type(4)));
typedef float f32x4 __attribute__((ext_vector_type(4)));

__device__ __forceinline__ f32x4 mfma16(half8v a, half8v b, f32x4 c) {
    return __builtin_amdgcn_mfma_f32_16x16x32_f16(a, b, c, 0, 0, 0);
}

__device__ __forceinline__ void load_lds16(const void* g, void* l) {
    __builtin_amdgcn_global_load_lds(
        (const __attribute__((address_space(1))) void*)g,
        (__attribute__((address_space(3))) void*)l, 16, 0, 0);
}

// ---------------------------------------------------------------------------
// Conversion: x [M,K] fp32 -> xhi/xlo fp16 (same layout), via float4.
// ---------------------------------------------------------------------------
__global__ __launch_bounds__(256) void convert_x(
    const float4* __restrict__ x4, half4v* __restrict__ hi4,
    half4v* __restrict__ lo4, int n4)
{
    int i = blockIdx.x * 256 + threadIdx.x;
    if (i >= n4) return;
    float4 v = x4[i];
    half4v h, lo;
    h.x = (_Float16)v.x; lo.x = (_Float16)(v.x - (float)h.x);
    h.y = (_Float16)v.y; lo.y = (_Float16)(v.y - (float)h.y);
    h.z = (_Float16)v.z; lo.z = (_Float16)(v.z - (float)h.z);
    h.w = (_Float16)v.w; lo.w = (_Float16)(v.w - (float)h.w);
    hi4[i] = h; lo4[i] = lo;
}

// Weights [K,1024] fp32 -> transposed hi/lo fp16 [3][1024][K].
__global__ __launch_bounds__(256) void convert_wt(
    const float* __restrict__ kz, const float* __restrict__ kr,
    const float* __restrict__ kh, _Float16* __restrict__ wth,
    _Float16* __restrict__ wtl)
{
    int gid = blockIdx.x * 256 + threadIdx.x;   // 3*1024*512
    int k = gid & (K_DIM - 1);
    int n = (gid >> 9) & (H_DIM - 1);
    int wsel = gid >> 19;                        // uniform per block
    const float* s = (wsel == 0) ? kz : ((wsel == 1) ? kr : kh);
    float v = s[(size_t)k * H_DIM + n];
    _Float16 h = (_Float16)v;
    wth[gid] = h;
    wtl[gid] = (_Float16)(v - (float)h);
}

// ---------------------------------------------------------------------------
// MFMA GEMM: C[M,3072] = A[M,512] * Bt[3072,512]^T with fp16 3-term split.
// 128x128 block tile, 4 waves each computing 64x64 (4x4 grid of 16x16x32).
// Output column range selects destination (XZ | XR | OUT).
// ---------------------------------------------------------------------------
__global__ __launch_bounds__(256) void gemm_mfma_split(
    const _Float16* __restrict__ Ahi, const _Float16* __restrict__ Alo,
    const _Float16* __restrict__ Bthi, const _Float16* __restrict__ Btlo,
    float* __restrict__ XZ, float* __restrict__ XR, float* __restrict__ OUT)
{
    __shared__ _Float16 Ah[128 * 32];
    __shared__ _Float16 Al[128 * 32];
    __shared__ _Float16 Bh[128 * 32];
    __shared__ _Float16 Bl[128 * 32];

    const int tid = threadIdx.x;
    const int w = tid >> 6, l = tid & 63;
    const int l15 = l & 15, quad = l >> 4;
    const int bx = blockIdx.x, by = blockIdx.y;
    const long m0 = (long)by * 128;
    const long n0 = (long)bx * 128;

    f32x4 acc[4][4] = {};

    // staging: 512 16B-slots per tile, thread covers slots tid and tid+256.
    const int s1 = tid, s2 = tid + 256;
    const long aoff1 = (m0 + (s1 >> 2)) * K_DIM + (s1 & 3) * 8;
    const long aoff2 = (m0 + (s2 >> 2)) * K_DIM + (s2 & 3) * 8;
    const long boff1 = (n0 + (s1 >> 2)) * K_DIM + (s1 & 3) * 8;
    const long boff2 = (n0 + (s2 >> 2)) * K_DIM + (s2 & 3) * 8;

    const _Float16* a1 = Ahi + aoff1;  const _Float16* a2 = Ahi + aoff2;
    const _Float16* q1 = Alo + aoff1;  const _Float16* q2 = Alo + aoff2;
    const _Float16* b1 = Bthi + boff1; const _Float16* b2 = Bthi + boff2;
    const _Float16* c1 = Btlo + boff1; const _Float16* c2 = Btlo + boff2;

    // wave-uniform LDS bases (halfs): slot s -> offset s*8
    _Float16* ldsA1 = &Ah[w * 512]; _Float16* ldsA2 = &Ah[2048 + w * 512];
    _Float16* ldsQ1 = &Al[w * 512]; _Float16* ldsQ2 = &Al[2048 + w * 512];
    _Float16* ldsB1 = &Bh[w * 512]; _Float16* ldsB2 = &Bh[2048 + w * 512];
    _Float16* ldsC1 = &Bl[w * 512]; _Float16* ldsC2 = &Bl[2048 + w * 512];

    const int wm = (w >> 1) * 64, wn = (w & 1) * 64;

    for (int kk = 0; kk < K_DIM / 32; ++kk) {
        load_lds16(a1, ldsA1); load_lds16(a2, ldsA2);
        load_lds16(q1, ldsQ1); load_lds16(q2, ldsQ2);
        load_lds16(b1, ldsB1); load_lds16(b2, ldsB2);
        load_lds16(c1, ldsC1); load_lds16(c2, ldsC2);
        a1 += 32; a2 += 32; q1 += 32; q2 += 32;
        b1 += 32; b2 += 32; c1 += 32; c2 += 32;
        __syncthreads();

        half8v afh[4], afl[4], bfh[4], bfl[4];
#pragma unroll
        for (int mi = 0; mi < 4; ++mi) {
            int row = (wm + mi * 16 + l15) * 32 + quad * 8;
            afh[mi] = *(const half8v*)&Ah[row];
            afl[mi] = *(const half8v*)&Al[row];
        }
#pragma unroll
        for (int ni = 0; ni < 4; ++ni) {
            int row = (wn + ni * 16 + l15) * 32 + quad * 8;
            bfh[ni] = *(const half8v*)&Bh[row];
            bfl[ni] = *(const half8v*)&Bl[row];
        }
#pragma unroll
        for (int mi = 0; mi < 4; ++mi)
#pragma unroll
            for (int ni = 0; ni < 4; ++ni) {
                acc[mi][ni] = mfma16(afh[mi], bfh[ni], acc[mi][ni]);
                acc[mi][ni] = mfma16(afh[mi], bfl[ni], acc[mi][ni]);
                acc[mi][ni] = mfma16(afl[mi], bfh[ni], acc[mi][ni]);
            }
        __syncthreads();
    }

    // Epilogue: C/D layout col=lane&15, row=quad*4+i.
    float* dst = (bx < 8) ? XZ : ((bx < 16) ? XR : OUT);
    const long nl = (long)(bx & 7) * 128 + wn + l15;
#pragma unroll
    for (int mi = 0; mi < 4; ++mi) {
        const long m = m0 + wm + mi * 16 + quad * 4;
#pragma unroll
        for (int ni = 0; ni < 4; ++ni) {
            float* p = dst + m * H_DIM + nl + ni * 16;
#pragma unroll
            for (int i = 0; i < 4; ++i)
                p[(long)i * H_DIM] = acc[mi][ni][i];
        }
    }
}

// ---------------------------------------------------------------------------
// Fallback fp32 GEMM (round 0)
// ---------------------------------------------------------------------------
#define BM 128
#define BN 128
#define BK 8
__global__ __launch_bounds__(256) void gemm_f32(
    const float* __restrict__ A, const float* __restrict__ B,
    float* __restrict__ C, int M, int N, int K)
{
    __shared__ float As[BK][BM];
    __shared__ float Bs[BK][BN];
    const int tid = threadIdx.x;
    const int bm = blockIdx.y * BM, bn = blockIdx.x * BN;
    const int tx = tid & 15, ty = tid >> 4;
    float acc[8][8];
#pragma unroll
    for (int i = 0; i < 8; i++)
#pragma unroll
        for (int j = 0; j < 8; j++) acc[i][j] = 0.f;
    const int a_row = tid >> 1, a_k = (tid & 1) * 4;
    const int b_row = tid >> 5, b_col = (tid & 31) * 4;
    const float* Aptr = A + (size_t)(bm + a_row) * K + a_k;
    const float* Bptr = B + (size_t)b_row * N + bn + b_col;
    for (int k0 = 0; k0 < K; k0 += BK) {
        float4 av = *(const float4*)(Aptr + k0);
        float4 bv = *(const float4*)(Bptr + (size_t)k0 * N);
        As[a_k + 0][a_row] = av.x; As[a_k + 1][a_row] = av.y;
        As[a_k + 2][a_row] = av.z; As[a_k + 3][a_row] = av.w;
        *(float4*)&Bs[b_row][b_col] = bv;
        __syncthreads();
#pragma unroll
        for (int kk = 0; kk < BK; kk++) {
            float4 a0 = *(const float4*)&As[kk][ty * 8];
            float4 a1 = *(const float4*)&As[kk][ty * 8 + 4];
            float4 b0 = *(const float4*)&Bs[kk][tx * 8];
            float4 b1 = *(const float4*)&Bs[kk][tx * 8 + 4];
            float a[8] = {a0.x, a0.y, a0.z, a0.w, a1.x, a1.y, a1.z, a1.w};
            float b[8] = {b0.x, b0.y, b0.z, b0.w, b1.x, b1.y, b1.z, b1.w};
#pragma unroll
            for (int i = 0; i < 8; i++)
#pragma unroll
                for (int j = 0; j < 8; j++)
                    acc[i][j] = fmaf(a[i], b[j], acc[i][j]);
        }
        __syncthreads();
    }
    float* Cptr = C + (size_t)(bm + ty * 8) * N + bn + tx * 8;
#pragma unroll
    for (int i = 0; i < 8; i++) {
        float4 c0 = {acc[i][0], acc[i][1], acc[i][2], acc[i][3]};
        float4 c1 = {acc[i][4], acc[i][5], acc[i][6], acc[i][7]};
        *(float4*)(Cptr + (size_t)i * N)     = c0;
        *(float4*)(Cptr + (size_t)i * N + 4) = c1;
    }
}

// ---------------------------------------------------------------------------
// Scan, 8-deep software pipeline. OUT holds xh on entry, h_t on exit.
// ---------------------------------------------------------------------------
__device__ __forceinline__ float fast_tanh(float x) {
    return 1.0f - 2.0f / (__expf(2.0f * x) + 1.0f);
}
__device__ __forceinline__ float fast_sigmoid(float x) {
    return 1.0f / (1.0f + __expf(-x));
}

__global__ __launch_bounds__(256) void scan_kernel(
    const float* __restrict__ XZ, const float* __restrict__ XR,
    float* __restrict__ OUT,
    const float* __restrict__ mz, const float* __restrict__ mr,
    const float* __restrict__ br, const float* __restrict__ bz)
{
    const int gid = blockIdx.x * blockDim.x + threadIdx.x;
    const int b = gid >> 10;          // H=1024
    const int h = gid & (H_DIM - 1);

    const float mzv = mz[h], mrv = mr[h], brv = br[h], bzv = bz[h];
    float hs = 0.f;
    size_t idx = (size_t)b * 512 * H_DIM + h;

    float cz[8], cr[8], ch[8];
#pragma unroll
    for (int j = 0; j < 8; ++j) {
        cz[j] = XZ[idx + (size_t)j * H_DIM];
        cr[j] = XR[idx + (size_t)j * H_DIM];
        ch[j] = OUT[idx + (size_t)j * H_DIM];
    }
    for (int t0 = 0; t0 < 512; t0 += 8) {
        float nz[8], nr[8], nh[8];
        const bool more = (t0 + 8) < 512;
        const size_t nidx = idx + 8ul * H_DIM;
        if (more) {
#pragma unroll
            for (int j = 0; j < 8; ++j) {
                nz[j] = XZ[nidx + (size_t)j * H_DIM];
                nr[j] = XR[nidx + (size_t)j * H_DIM];
                nh[j] = OUT[nidx + (size_t)j * H_DIM];
            }
        }
#pragma unroll
        for (int j = 0; j < 8; ++j) {
            const float r = fast_tanh(fmaf(hs, mrv, cr[j]) + brv) + 1.0f;
            const float z = fast_sigmoid(fmaf(hs, mzv, cz[j]) + bzv);
            const float hn = fmaf(z, hs, (1.0f - z) * fast_tanh(fmaf(r, hs, ch[j])));
            OUT[idx + (size_t)j * H_DIM] = hn;
            hs = hn;
        }
        idx = nidx;
        if (more) {
#pragma unroll
            for (int j = 0; j < 8; ++j) { cz[j] = nz[j]; cr[j] = nr[j]; ch[j] = nh[j]; }
        }
    }
}

// ---------------------------------------------------------------------------
extern "C" void kernel_launch(void* const* d_in, const int* in_sizes, int n_in,
                              void* d_out, int out_size, void* d_ws, size_t ws_size,
                              hipStream_t stream) {
    const float* x  = (const float*)d_in[0];
    const float* kz = (const float*)d_in[1];
    const float* kr = (const float*)d_in[2];
    const float* kh = (const float*)d_in[3];
    const float* mz = (const float*)d_in[4];
    const float* mr = (const float*)d_in[5];
    const float* br = (const float*)d_in[6];
    const float* bz = (const float*)d_in[7];
    float* out = (float*)d_out;

    char* ws = (char*)d_ws;
    float* XZ = (float*)ws;                              // 128 MiB
    float* XR = (float*)(ws + 134217728ul);              // 128 MiB
    _Float16* XHI = (_Float16*)(ws + 268435456ul);       // 32 MiB
    _Float16* XLO = (_Float16*)(ws + 301989888ul);       // 32 MiB
    _Float16* WTH = (_Float16*)(ws + 335544320ul);       // 3 MiB
    _Float16* WTL = (_Float16*)(ws + 338690048ul);       // 3 MiB
    const size_t need = 341835776ul;

    if (ws_size >= need) {
        int n4 = M_DIM * K_DIM / 4;                      // 4.19M
        convert_x<<<n4 / 256, 256, 0, stream>>>(
            (const float4*)x, (half4v*)XHI, (half4v*)XLO, n4);
        convert_wt<<<(3 * H_DIM * K_DIM) / 256, 256, 0, stream>>>(
            kz, kr, kh, WTH, WTL);
        dim3 grid(N3 / 128, M_DIM / 128);                // 24 x 256
        gemm_mfma_split<<<grid, 256, 0, stream>>>(
            XHI, XLO, WTH, WTL, XZ, XR, out);
    } else {
        dim3 grid(H_DIM / BN, M_DIM / BM);
        gemm_f32<<<grid, 256, 0, stream>>>(x, kz, XZ,  M_DIM, H_DIM, K_DIM);
        gemm_f32<<<grid, 256, 0, stream>>>(x, kr, XR,  M_DIM, H_DIM, K_DIM);
        gemm_f32<<<grid, 256, 0, stream>>>(x, kh, out, M_DIM, H_DIM, K_DIM);
    }

    scan_kernel<<<(64 * H_DIM) / 256, 256, 0, stream>>>(
        XZ, XR, out, mz, mr, br, bz);
}